// Round 1
// baseline (821.615 us; speedup 1.0000x reference)
//
#include <hip/hip_runtime.h>
#include <math.h>

#define NB 16        // batch
#define CH 256       // hidden
#define CND 512      // cond channels
#define NH 4
#define KC 64
#define TTT 2048
#define TSS 512

// ---------------------------------------------------------------------------
// Generic tiled GEMM: Y[b] = W @ X[b] + bias
// W: [M,K] row-major, X: [B,K,T], Y: [B,M,T]. Grid (T/64, M/64, B), block 256.
// ---------------------------------------------------------------------------
__global__ __launch_bounds__(256) void gemm_bias_kernel(
    const float* __restrict__ W, const float* __restrict__ bias,
    const float* __restrict__ X, float* __restrict__ Y,
    int M, int K, int T) {
  const int t0 = blockIdx.x * 64;
  const int m0 = blockIdx.y * 64;
  const int b  = blockIdx.z;
  const int tid = threadIdx.x;
  const int tx = tid & 15, ty = tid >> 4;

  __shared__ float As[16][68];
  __shared__ float Bs[16][64];

  const float* Xb = X + (size_t)b * K * T;
  float acc[4][4] = {};

  const int m_a = tid >> 2, k_a = (tid & 3) * 4;
  const int k_b = tid >> 4, n_b = (tid & 15) * 4;

  for (int k0 = 0; k0 < K; k0 += 16) {
    float4 av = *(const float4*)&W[(size_t)(m0 + m_a) * K + k0 + k_a];
    As[k_a + 0][m_a] = av.x;
    As[k_a + 1][m_a] = av.y;
    As[k_a + 2][m_a] = av.z;
    As[k_a + 3][m_a] = av.w;
    *(float4*)&Bs[k_b][n_b] = *(const float4*)&Xb[(size_t)(k0 + k_b) * T + t0 + n_b];
    __syncthreads();
#pragma unroll
    for (int kk = 0; kk < 16; ++kk) {
      float a0 = As[kk][ty * 4 + 0], a1 = As[kk][ty * 4 + 1];
      float a2 = As[kk][ty * 4 + 2], a3 = As[kk][ty * 4 + 3];
      float b0 = Bs[kk][tx * 4 + 0], b1 = Bs[kk][tx * 4 + 1];
      float b2 = Bs[kk][tx * 4 + 2], b3 = Bs[kk][tx * 4 + 3];
      acc[0][0] += a0 * b0; acc[0][1] += a0 * b1; acc[0][2] += a0 * b2; acc[0][3] += a0 * b3;
      acc[1][0] += a1 * b0; acc[1][1] += a1 * b1; acc[1][2] += a1 * b2; acc[1][3] += a1 * b3;
      acc[2][0] += a2 * b0; acc[2][1] += a2 * b1; acc[2][2] += a2 * b2; acc[2][3] += a2 * b3;
      acc[3][0] += a3 * b0; acc[3][1] += a3 * b1; acc[3][2] += a3 * b2; acc[3][3] += a3 * b3;
    }
    __syncthreads();
  }
#pragma unroll
  for (int i = 0; i < 4; ++i) {
    int m = m0 + ty * 4 + i;
    float bi = bias[m];
    float4 ov;
    ov.x = acc[i][0] + bi; ov.y = acc[i][1] + bi;
    ov.z = acc[i][2] + bi; ov.w = acc[i][3] + bi;
    *(float4*)&Y[((size_t)b * M + m) * T + t0 + tx * 4] = ov;
  }
}

// ---------------------------------------------------------------------------
// In-place RoPE: buf [B, 256, T]. Each thread rotates the (j, j+32) pair of
// one (b,h,t) so the in-place update is race-free.
// idx = ((b*NH + h)*32 + j)*T + t
// ---------------------------------------------------------------------------
__global__ __launch_bounds__(256) void rope_kernel(float* buf, int T, int tlog2) {
  int idx = blockIdx.x * 256 + threadIdx.x;
  int t = idx & (T - 1);
  int r = idx >> tlog2;
  int j = r & 31; r >>= 5;
  int h = r & 3;
  int b = r >> 2;
  if (b >= NB) return;
  // inv_freq = 10000^(-j/32) = exp(-j * ln(10000)/32)
  float invf = expf(-(float)j * 0.28782313662425572f);
  float ang = (float)t * invf;
  float cs = cosf(ang), sn = sinf(ang);
  size_t base = ((size_t)(b * CH + h * KC + j)) * T + t;
  float q1 = buf[base];
  float q2 = buf[base + (size_t)32 * T];
  buf[base] = q1 * cs - q2 * sn;
  buf[base + (size_t)32 * T] = q2 * cs + q1 * sn;
}

// ---------------------------------------------------------------------------
// Attention: one block per (b, h, 64-row Q tile). Single-pass softmax (scores
// are small; no max subtraction needed; masked -> exp(-1e4)==0).
// q/k/v layout: [B, 256, T] channel-major. Output written in place over qbuf.
// ---------------------------------------------------------------------------
__global__ __launch_bounds__(256) void attn_kernel(
    const float* qbuf, const float* __restrict__ kbuf,
    const float* __restrict__ vbuf, const float* __restrict__ cond_mask,
    float* obuf) {
  const int t0 = blockIdx.x * 64;
  const int h  = blockIdx.y;
  const int b  = blockIdx.z;
  const int tid = threadIdx.x;
  const int tx = tid & 15, ty = tid >> 4;

  __shared__ float Qs[64][68];
  __shared__ float Ks[32][68];
  __shared__ float Vs[32][68];
  __shared__ float Es[64][33];
  __shared__ float denom_s[64];

  const float* qb = qbuf + ((size_t)(b * CH + h * KC)) * TTT + t0;
#pragma unroll
  for (int r = 0; r < 16; ++r) {
    int idx = tid + r * 256;          // 0..4095
    int j = idx >> 6, t = idx & 63;
    Qs[t][j] = qb[(size_t)j * TTT + t];
  }
  float acc[4][4] = {};
  float dacc = 0.f;
  __syncthreads();

  const float* kb = kbuf + ((size_t)(b * CH + h * KC)) * TSS;
  const float* vb = vbuf + ((size_t)(b * CH + h * KC)) * TSS;
  const float* cm = cond_mask + (size_t)b * TSS;

  for (int s0 = 0; s0 < TSS; s0 += 32) {
#pragma unroll
    for (int r = 0; r < 8; ++r) {
      int idx = tid + r * 256;        // 0..2047
      int j = idx >> 5, s = idx & 31;
      Ks[s][j] = kb[(size_t)j * TSS + s0 + s];
      Vs[s][j] = vb[(size_t)j * TSS + s0 + s];
    }
    __syncthreads();

    // S fragment: rows ty*4..+3, cols tx*2, tx*2+1
    float s00 = 0.f, s01 = 0.f, s10 = 0.f, s11 = 0.f, s20 = 0.f, s21 = 0.f, s30 = 0.f, s31 = 0.f;
    for (int j = 0; j < 64; ++j) {
      float b0 = Ks[tx * 2 + 0][j];
      float b1 = Ks[tx * 2 + 1][j];
      float a0 = Qs[ty * 4 + 0][j], a1 = Qs[ty * 4 + 1][j];
      float a2 = Qs[ty * 4 + 2][j], a3 = Qs[ty * 4 + 3][j];
      s00 += a0 * b0; s01 += a0 * b1;
      s10 += a1 * b0; s11 += a1 * b1;
      s20 += a2 * b0; s21 += a2 * b1;
      s30 += a3 * b0; s31 += a3 * b1;
    }
    float mk0 = (cm[s0 + tx * 2 + 0] != 0.f) ? 1.f : 0.f;
    float mk1 = (cm[s0 + tx * 2 + 1] != 0.f) ? 1.f : 0.f;
    Es[ty * 4 + 0][tx * 2 + 0] = expf(0.125f * s00) * mk0;
    Es[ty * 4 + 0][tx * 2 + 1] = expf(0.125f * s01) * mk1;
    Es[ty * 4 + 1][tx * 2 + 0] = expf(0.125f * s10) * mk0;
    Es[ty * 4 + 1][tx * 2 + 1] = expf(0.125f * s11) * mk1;
    Es[ty * 4 + 2][tx * 2 + 0] = expf(0.125f * s20) * mk0;
    Es[ty * 4 + 2][tx * 2 + 1] = expf(0.125f * s21) * mk1;
    Es[ty * 4 + 3][tx * 2 + 0] = expf(0.125f * s30) * mk0;
    Es[ty * 4 + 3][tx * 2 + 1] = expf(0.125f * s31) * mk1;
    __syncthreads();

    if (tid < 64) {
      float d = 0.f;
      for (int s = 0; s < 32; ++s) d += Es[tid][s];
      dacc += d;
    }
    for (int s = 0; s < 32; ++s) {
      float v0 = Vs[s][tx * 4 + 0], v1 = Vs[s][tx * 4 + 1];
      float v2 = Vs[s][tx * 4 + 2], v3 = Vs[s][tx * 4 + 3];
      float e0 = Es[ty * 4 + 0][s], e1 = Es[ty * 4 + 1][s];
      float e2 = Es[ty * 4 + 2][s], e3 = Es[ty * 4 + 3][s];
      acc[0][0] += e0 * v0; acc[0][1] += e0 * v1; acc[0][2] += e0 * v2; acc[0][3] += e0 * v3;
      acc[1][0] += e1 * v0; acc[1][1] += e1 * v1; acc[1][2] += e1 * v2; acc[1][3] += e1 * v3;
      acc[2][0] += e2 * v0; acc[2][1] += e2 * v1; acc[2][2] += e2 * v2; acc[2][3] += e2 * v3;
      acc[3][0] += e3 * v0; acc[3][1] += e3 * v1; acc[3][2] += e3 * v2; acc[3][3] += e3 * v3;
    }
    __syncthreads();
  }

  if (tid < 64) denom_s[tid] = dacc;
  __syncthreads();

  float rd[4];
#pragma unroll
  for (int i = 0; i < 4; ++i) rd[i] = 1.f / fmaxf(denom_s[ty * 4 + i], 1e-30f);

  // transpose through LDS (reuse Qs as Os[j][t]) for coalesced store
#pragma unroll
  for (int i = 0; i < 4; ++i)
#pragma unroll
    for (int l = 0; l < 4; ++l)
      Qs[tx * 4 + l][ty * 4 + i] = acc[i][l] * rd[i];
  __syncthreads();

  float* ob = obuf + ((size_t)(b * CH + h * KC)) * TTT + t0;
#pragma unroll
  for (int r = 0; r < 16; ++r) {
    int idx = tid + r * 256;
    int j = idx >> 6, t = idx & 63;
    ob[(size_t)j * TTT + t] = Qs[j][t];
  }
}

// ---------------------------------------------------------------------------
// Film: gb = w_film @ y + b_film; out = (x*gamma + beta) * x_mask
// w_film: [512,256]; gamma rows [0,256), beta rows [256,512).
// Grid (2048/64, 256/64, B), block 256.
// ---------------------------------------------------------------------------
__global__ __launch_bounds__(256) void film_kernel(
    const float* __restrict__ wf, const float* __restrict__ bf,
    const float* __restrict__ Yb, const float* __restrict__ X,
    const float* __restrict__ xmask, float* __restrict__ out) {
  const int t0 = blockIdx.x * 64;
  const int m0 = blockIdx.y * 64;
  const int b  = blockIdx.z;
  const int tid = threadIdx.x;
  const int tx = tid & 15, ty = tid >> 4;

  __shared__ float Ag[16][68];
  __shared__ float Ab[16][68];
  __shared__ float Bs[16][64];

  const float* Y = Yb + (size_t)b * CH * TTT;
  float accg[4][4] = {}, accb[4][4] = {};

  const int m_a = tid >> 2, k_a = (tid & 3) * 4;
  const int k_b = tid >> 4, n_b = (tid & 15) * 4;

  for (int k0 = 0; k0 < 256; k0 += 16) {
    float4 ag = *(const float4*)&wf[(size_t)(m0 + m_a) * 256 + k0 + k_a];
    float4 ab = *(const float4*)&wf[(size_t)(256 + m0 + m_a) * 256 + k0 + k_a];
    Ag[k_a + 0][m_a] = ag.x; Ag[k_a + 1][m_a] = ag.y;
    Ag[k_a + 2][m_a] = ag.z; Ag[k_a + 3][m_a] = ag.w;
    Ab[k_a + 0][m_a] = ab.x; Ab[k_a + 1][m_a] = ab.y;
    Ab[k_a + 2][m_a] = ab.z; Ab[k_a + 3][m_a] = ab.w;
    *(float4*)&Bs[k_b][n_b] = *(const float4*)&Y[(size_t)(k0 + k_b) * TTT + t0 + n_b];
    __syncthreads();
#pragma unroll
    for (int kk = 0; kk < 16; ++kk) {
      float b0 = Bs[kk][tx * 4 + 0], b1 = Bs[kk][tx * 4 + 1];
      float b2 = Bs[kk][tx * 4 + 2], b3 = Bs[kk][tx * 4 + 3];
#pragma unroll
      for (int i = 0; i < 4; ++i) {
        float g = Ag[kk][ty * 4 + i];
        float w = Ab[kk][ty * 4 + i];
        accg[i][0] += g * b0; accg[i][1] += g * b1; accg[i][2] += g * b2; accg[i][3] += g * b3;
        accb[i][0] += w * b0; accb[i][1] += w * b1; accb[i][2] += w * b2; accb[i][3] += w * b3;
      }
    }
    __syncthreads();
  }

  const float* Xb = X + (size_t)b * CH * TTT;
  const float* xm = xmask + (size_t)b * TTT;
  int t = t0 + tx * 4;
  float4 xmv = *(const float4*)&xm[t];
#pragma unroll
  for (int i = 0; i < 4; ++i) {
    int o = m0 + ty * 4 + i;
    float bg = bf[o], bb = bf[256 + o];
    float4 xv = *(const float4*)&Xb[(size_t)o * TTT + t];
    float4 ov;
    ov.x = (xv.x * (accg[i][0] + bg) + accb[i][0] + bb) * xmv.x;
    ov.y = (xv.y * (accg[i][1] + bg) + accb[i][1] + bb) * xmv.y;
    ov.z = (xv.z * (accg[i][2] + bg) + accb[i][2] + bb) * xmv.z;
    ov.w = (xv.w * (accg[i][3] + bg) + accb[i][3] + bb) * xmv.w;
    *(float4*)&out[((size_t)b * CH + o) * TTT + t] = ov;
  }
}

// ---------------------------------------------------------------------------
extern "C" void kernel_launch(void* const* d_in, const int* in_sizes, int n_in,
                              void* d_out, int out_size, void* d_ws, size_t ws_size,
                              hipStream_t stream) {
  const float* x           = (const float*)d_in[0];
  const float* x_mask      = (const float*)d_in[1];
  const float* cond_latent = (const float*)d_in[2];
  const float* cond_mask   = (const float*)d_in[3];
  const float* w_cond      = (const float*)d_in[4];
  const float* b_cond      = (const float*)d_in[5];
  const float* wq          = (const float*)d_in[6];
  const float* bq          = (const float*)d_in[7];
  const float* wk          = (const float*)d_in[8];
  const float* bk          = (const float*)d_in[9];
  const float* wv          = (const float*)d_in[10];
  const float* bv          = (const float*)d_in[11];
  const float* wo          = (const float*)d_in[12];
  const float* bo          = (const float*)d_in[13];
  const float* w_film      = (const float*)d_in[14];
  const float* b_film      = (const float*)d_in[15];
  float* out = (float*)d_out;

  float* ws = (float*)d_ws;
  float* c_buf = ws;                    // 16*256*512  = 2,097,152
  float* q_buf = c_buf + 2097152;       // 16*256*2048 = 8,388,608 (reused as attn out)
  float* k_buf = q_buf + 8388608;       // 2,097,152
  float* v_buf = k_buf + 2097152;       // 2,097,152
  float* y_buf = v_buf + 2097152;       // 8,388,608
  // total 92.3 MB

  dim3 blk(256);

  // c = w_cond @ cond_latent + b_cond        [16,256,512]
  gemm_bias_kernel<<<dim3(8, 4, 16), blk, 0, stream>>>(w_cond, b_cond, cond_latent, c_buf, 256, 512, 512);
  // q = wq @ x + bq                          [16,256,2048]
  gemm_bias_kernel<<<dim3(32, 4, 16), blk, 0, stream>>>(wq, bq, x, q_buf, 256, 256, 2048);
  // k = wk @ c + bk                          [16,256,512]
  gemm_bias_kernel<<<dim3(8, 4, 16), blk, 0, stream>>>(wk, bk, c_buf, k_buf, 256, 256, 512);
  // v = wv @ c + bv
  gemm_bias_kernel<<<dim3(8, 4, 16), blk, 0, stream>>>(wv, bv, c_buf, v_buf, 256, 256, 512);
  // RoPE in place
  rope_kernel<<<16384, blk, 0, stream>>>(q_buf, 2048, 11);
  rope_kernel<<<4096, blk, 0, stream>>>(k_buf, 512, 9);
  // attention (writes output in place over q_buf)
  attn_kernel<<<dim3(32, 4, 16), blk, 0, stream>>>(q_buf, k_buf, v_buf, cond_mask, q_buf);
  // y = wo @ attn + bo
  gemm_bias_kernel<<<dim3(32, 4, 16), blk, 0, stream>>>(wo, bo, q_buf, y_buf, 256, 256, 2048);
  // film + final output
  film_kernel<<<dim3(32, 4, 16), blk, 0, stream>>>(w_film, b_film, y_buf, x, x_mask, out);
}

// Round 3
// 727.977 us; speedup vs baseline: 1.1286x; 1.1286x over previous
//
#include <hip/hip_runtime.h>
#include <math.h>

#define NB 16        // batch
#define CH 256       // hidden
#define CND 512      // cond channels
#define NH 4
#define KC 64
#define TTT 2048
#define TSS 512

// ---------------------------------------------------------------------------
// Templated tiled GEMM: Yn[b] = Wn @ X[b] + bn   (n < NOUT)
// W: [M,K] row-major, X: [B,K,T], Y: [B,256,T].
// Tile: 64 rows x (16*TN) cols, BK=32. Block 256. Grid (T/(16TN), M/64, B).
// Microtile: 4 rows (4ty+i) x TN cols (4tx+u+64g).
// ---------------------------------------------------------------------------
template <int TN, int NOUT>
__global__ __launch_bounds__(256) void gemm_v2(
    const float* __restrict__ W0, const float* __restrict__ b0,
    const float* __restrict__ W1, const float* __restrict__ b1,
    const float* __restrict__ X, float* __restrict__ Y0, float* __restrict__ Y1,
    int K, int T) {
  constexpr int TT = 16 * TN;       // 64 or 128
  constexpr int TQ = TT / 4;        // float4s per k-row
  constexpr int PB = (32 * TQ) / 256;
  const int t0 = blockIdx.x * TT;
  const int m0 = blockIdx.y * 64;
  const int b  = blockIdx.z;
  const int tid = threadIdx.x;
  const int tx = tid & 15, ty = tid >> 4;

  __shared__ float As[NOUT][32][68];
  __shared__ float Bs[32][TT + 4];

  const float* Xb = X + (size_t)b * K * T;
  float acc[NOUT][4][TN];
#pragma unroll
  for (int n = 0; n < NOUT; ++n)
#pragma unroll
    for (int i = 0; i < 4; ++i)
#pragma unroll
      for (int u = 0; u < TN; ++u) acc[n][i][u] = 0.f;

  const int am = tid >> 2, akq = tid & 3;   // A staging: m=am, k-quads akq, akq+4

  for (int k0 = 0; k0 < K; k0 += 32) {
#pragma unroll
    for (int n = 0; n < NOUT; ++n) {
      const float* Wn = (n == 0) ? W0 : W1;
      float4 a0 = *(const float4*)&Wn[(size_t)(m0 + am) * K + k0 + 4 * akq];
      float4 a1 = *(const float4*)&Wn[(size_t)(m0 + am) * K + k0 + 16 + 4 * akq];
      As[n][4 * akq + 0][am] = a0.x; As[n][4 * akq + 1][am] = a0.y;
      As[n][4 * akq + 2][am] = a0.z; As[n][4 * akq + 3][am] = a0.w;
      As[n][16 + 4 * akq + 0][am] = a1.x; As[n][16 + 4 * akq + 1][am] = a1.y;
      As[n][16 + 4 * akq + 2][am] = a1.z; As[n][16 + 4 * akq + 3][am] = a1.w;
    }
#pragma unroll
    for (int p = 0; p < PB; ++p) {
      int idx = tid + p * 256;
      int t4 = idx & (TQ - 1), k = idx / TQ;
      *(float4*)&Bs[k][4 * t4] = *(const float4*)&Xb[(size_t)(k0 + k) * T + t0 + 4 * t4];
    }
    __syncthreads();
#pragma unroll
    for (int kk = 0; kk < 32; ++kk) {
      float4 av[NOUT];
#pragma unroll
      for (int n = 0; n < NOUT; ++n) av[n] = *(const float4*)&As[n][kk][4 * ty];
      float4 bv[TN / 4];
#pragma unroll
      for (int g = 0; g < TN / 4; ++g) bv[g] = *(const float4*)&Bs[kk][4 * tx + 64 * g];
#pragma unroll
      for (int n = 0; n < NOUT; ++n) {
        const float a4[4] = {av[n].x, av[n].y, av[n].z, av[n].w};
#pragma unroll
        for (int i = 0; i < 4; ++i)
#pragma unroll
          for (int g = 0; g < TN / 4; ++g) {
            acc[n][i][4 * g + 0] += a4[i] * bv[g].x;
            acc[n][i][4 * g + 1] += a4[i] * bv[g].y;
            acc[n][i][4 * g + 2] += a4[i] * bv[g].z;
            acc[n][i][4 * g + 3] += a4[i] * bv[g].w;
          }
      }
    }
    __syncthreads();
  }
#pragma unroll
  for (int n = 0; n < NOUT; ++n) {
    float* Yn = (n == 0) ? Y0 : Y1;
    const float* bn = (n == 0) ? b0 : b1;
#pragma unroll
    for (int i = 0; i < 4; ++i) {
      int row = m0 + 4 * ty + i;
      float bi = bn[row];
#pragma unroll
      for (int g = 0; g < TN / 4; ++g) {
        float4 ov;
        ov.x = acc[n][i][4 * g + 0] + bi; ov.y = acc[n][i][4 * g + 1] + bi;
        ov.z = acc[n][i][4 * g + 2] + bi; ov.w = acc[n][i][4 * g + 3] + bi;
        *(float4*)&Yn[((size_t)b * 256 + row) * T + t0 + 4 * tx + 64 * g] = ov;
      }
    }
  }
}

// ---------------------------------------------------------------------------
// In-place RoPE (precise sin/cos for large-arg reduction accuracy)
// ---------------------------------------------------------------------------
__global__ __launch_bounds__(256) void rope_kernel(float* buf, int T, int tlog2) {
  int idx = blockIdx.x * 256 + threadIdx.x;
  int t = idx & (T - 1);
  int r = idx >> tlog2;
  int j = r & 31; r >>= 5;
  int h = r & 3;
  int b = r >> 2;
  if (b >= NB) return;
  float invf = expf(-(float)j * 0.28782313662425572f);
  float ang = (float)t * invf;
  float cs = cosf(ang), sn = sinf(ang);
  size_t base = ((size_t)(b * CH + h * KC + j)) * T + t;
  float q1 = buf[base];
  float q2 = buf[base + (size_t)32 * T];
  buf[base] = q1 * cs - q2 * sn;
  buf[base + (size_t)32 * T] = q2 * cs + q1 * sn;
}

// ---------------------------------------------------------------------------
// Attention v2: block = (b, h, 64 q-rows). All inner LDS reads are b64,
// broadcast or conflict-free. E round-trips through the dead K buffer.
// Fragment map: rows r = 2ty+d+32i, cols c = 2tx+e+32l, out-chans ch = tx+16m.
// Single-pass softmax (scores tiny; masked cols give exp(-1e4)=0 exactly).
// ---------------------------------------------------------------------------
__global__ __launch_bounds__(256) void attn_v2(
    const float* __restrict__ qbuf, const float* __restrict__ kbuf,
    const float* __restrict__ vbuf, const float* __restrict__ cond_mask,
    float* __restrict__ obuf) {
  const int t0 = blockIdx.x * 64;
  const int h  = blockIdx.y;
  const int b  = blockIdx.z;
  const int tid = threadIdx.x;
  const int tx = tid & 15, ty = tid >> 4;

  __shared__ float Qs[64][64];   // [j][t]   (reads broadcast over tx)
  __shared__ float KEs[64][68];  // K: [j][s] then E: [r][c] then O: [ch][t]
  __shared__ float Vs[64][68];   // [ch][s]  (stride 68 -> V reads 2-way = free)

  const float* qb = qbuf + ((size_t)(b * CH + h * KC)) * TTT + t0;
#pragma unroll
  for (int p = 0; p < 4; ++p) {
    int idx = tid + p * 256;
    int j = idx >> 4, t4 = idx & 15;
    *(float4*)&Qs[j][4 * t4] = *(const float4*)&qb[(size_t)j * TTT + 4 * t4];
  }

  float acc_o[4][4] = {};  // [row(i,d)][m]
  float dden[4] = {};      // row denominators

  const float* kb = kbuf + ((size_t)(b * CH + h * KC)) * TSS;
  const float* vb = vbuf + ((size_t)(b * CH + h * KC)) * TSS;
  const float* cm = cond_mask + (size_t)b * TSS;

  const int rw[4] = {2 * ty, 2 * ty + 1, 2 * ty + 32, 2 * ty + 33};

  for (int s0 = 0; s0 < TSS; s0 += 64) {
    // stage K -> KEs, V -> Vs (direct copies, channel-major)
#pragma unroll
    for (int p = 0; p < 4; ++p) {
      int idx = tid + p * 256;
      int j = idx >> 4, s4 = idx & 15;
      *(float4*)&KEs[j][4 * s4] = *(const float4*)&kb[(size_t)j * TSS + s0 + 4 * s4];
      *(float4*)&Vs[j][4 * s4]  = *(const float4*)&vb[(size_t)j * TSS + s0 + 4 * s4];
    }
    __syncthreads();

    // S = Q K^T  (b64 reads: Q broadcast over tx, K conflict-free over tx)
    float acc_s[4][4] = {};
#pragma unroll 8
    for (int j = 0; j < 64; ++j) {
      float2 q0 = *(const float2*)&Qs[j][2 * ty];
      float2 q1 = *(const float2*)&Qs[j][2 * ty + 32];
      float2 k0 = *(const float2*)&KEs[j][2 * tx];
      float2 k1 = *(const float2*)&KEs[j][2 * tx + 32];
      const float qv[4] = {q0.x, q0.y, q1.x, q1.y};
      const float kv[4] = {k0.x, k0.y, k1.x, k1.y};
#pragma unroll
      for (int r = 0; r < 4; ++r)
#pragma unroll
        for (int c = 0; c < 4; ++c) acc_s[r][c] += qv[r] * kv[c];
    }
    __syncthreads();   // K reads done; KEs becomes E

    float mk[4];
    mk[0] = (cm[s0 + 2 * tx] != 0.f) ? 1.f : 0.f;
    mk[1] = (cm[s0 + 2 * tx + 1] != 0.f) ? 1.f : 0.f;
    mk[2] = (cm[s0 + 2 * tx + 32] != 0.f) ? 1.f : 0.f;
    mk[3] = (cm[s0 + 2 * tx + 33] != 0.f) ? 1.f : 0.f;
    const int cl[4] = {2 * tx, 2 * tx + 1, 2 * tx + 32, 2 * tx + 33};
#pragma unroll
    for (int r = 0; r < 4; ++r)
#pragma unroll
      for (int c = 0; c < 4; ++c) {
        float e = __expf(acc_s[r][c] * 0.125f) * mk[c];
        dden[r] += e;
        KEs[rw[r]][cl[c]] = e;
      }
    __syncthreads();

    // O += P V   (b64 reads: E broadcast over tx, V 2-way over tx)
#pragma unroll 4
    for (int q = 0; q < 32; ++q) {
      float2 ev[4], vv[4];
#pragma unroll
      for (int r = 0; r < 4; ++r) ev[r] = *(const float2*)&KEs[rw[r]][2 * q];
#pragma unroll
      for (int m = 0; m < 4; ++m) vv[m] = *(const float2*)&Vs[tx + 16 * m][2 * q];
#pragma unroll
      for (int r = 0; r < 4; ++r)
#pragma unroll
        for (int m = 0; m < 4; ++m)
          acc_o[r][m] += ev[r].x * vv[m].x + ev[r].y * vv[m].y;
    }
    __syncthreads();
  }

  // row denominators: butterfly over the 16 tx lanes (no LDS needed)
#pragma unroll
  for (int r = 0; r < 4; ++r) {
#pragma unroll
    for (int off = 1; off < 16; off <<= 1) dden[r] += __shfl_xor(dden[r], off, 16);
    dden[r] = 1.f / fmaxf(dden[r], 1e-30f);
  }

  // normalized O -> LDS transposed [ch][t], then coalesced f4 store (in-place ok)
#pragma unroll
  for (int r = 0; r < 4; ++r)
#pragma unroll
    for (int m = 0; m < 4; ++m)
      KEs[tx + 16 * m][rw[r]] = acc_o[r][m] * dden[r];
  __syncthreads();

  float* ob = obuf + ((size_t)(b * CH + h * KC)) * TTT + t0;
#pragma unroll
  for (int p = 0; p < 4; ++p) {
    int idx = tid + p * 256;
    int ch = idx >> 4, t4 = idx & 15;
    *(float4*)&ob[(size_t)ch * TTT + 4 * t4] = *(const float4*)&KEs[ch][4 * t4];
  }
}

// ---------------------------------------------------------------------------
// Film: gb = w_film @ y + b_film; out = (x*gamma + beta) * x_mask
// Same structure as gemm_v2<8,2> with fused epilogue.
// ---------------------------------------------------------------------------
__global__ __launch_bounds__(256) void film_v2(
    const float* __restrict__ wf, const float* __restrict__ bfilm,
    const float* __restrict__ Yb, const float* __restrict__ X,
    const float* __restrict__ xmask, float* __restrict__ out) {
  const int t0 = blockIdx.x * 128;
  const int m0 = blockIdx.y * 64;
  const int b  = blockIdx.z;
  const int tid = threadIdx.x;
  const int tx = tid & 15, ty = tid >> 4;

  __shared__ float Ag[32][68];
  __shared__ float Ab[32][68];
  __shared__ float Bs[32][132];

  const float* Y = Yb + (size_t)b * CH * TTT;
  float accg[4][8], accb[4][8];
#pragma unroll
  for (int i = 0; i < 4; ++i)
#pragma unroll
    for (int u = 0; u < 8; ++u) { accg[i][u] = 0.f; accb[i][u] = 0.f; }

  const int am = tid >> 2, akq = tid & 3;

  for (int k0 = 0; k0 < 256; k0 += 32) {
    {
      float4 a0 = *(const float4*)&wf[(size_t)(m0 + am) * 256 + k0 + 4 * akq];
      float4 a1 = *(const float4*)&wf[(size_t)(m0 + am) * 256 + k0 + 16 + 4 * akq];
      Ag[4 * akq + 0][am] = a0.x; Ag[4 * akq + 1][am] = a0.y;
      Ag[4 * akq + 2][am] = a0.z; Ag[4 * akq + 3][am] = a0.w;
      Ag[16 + 4 * akq + 0][am] = a1.x; Ag[16 + 4 * akq + 1][am] = a1.y;
      Ag[16 + 4 * akq + 2][am] = a1.z; Ag[16 + 4 * akq + 3][am] = a1.w;
      float4 c0 = *(const float4*)&wf[(size_t)(256 + m0 + am) * 256 + k0 + 4 * akq];
      float4 c1 = *(const float4*)&wf[(size_t)(256 + m0 + am) * 256 + k0 + 16 + 4 * akq];
      Ab[4 * akq + 0][am] = c0.x; Ab[4 * akq + 1][am] = c0.y;
      Ab[4 * akq + 2][am] = c0.z; Ab[4 * akq + 3][am] = c0.w;
      Ab[16 + 4 * akq + 0][am] = c1.x; Ab[16 + 4 * akq + 1][am] = c1.y;
      Ab[16 + 4 * akq + 2][am] = c1.z; Ab[16 + 4 * akq + 3][am] = c1.w;
    }
#pragma unroll
    for (int p = 0; p < 4; ++p) {
      int idx = tid + p * 256;
      int t4 = idx & 31, k = idx >> 5;
      *(float4*)&Bs[k][4 * t4] = *(const float4*)&Y[(size_t)(k0 + k) * TTT + t0 + 4 * t4];
    }
    __syncthreads();
#pragma unroll
    for (int kk = 0; kk < 32; ++kk) {
      float4 ag = *(const float4*)&Ag[kk][4 * ty];
      float4 ab = *(const float4*)&Ab[kk][4 * ty];
      float4 bv0 = *(const float4*)&Bs[kk][4 * tx];
      float4 bv1 = *(const float4*)&Bs[kk][4 * tx + 64];
      const float g4[4] = {ag.x, ag.y, ag.z, ag.w};
      const float c4[4] = {ab.x, ab.y, ab.z, ab.w};
#pragma unroll
      for (int i = 0; i < 4; ++i) {
        accg[i][0] += g4[i] * bv0.x; accg[i][1] += g4[i] * bv0.y;
        accg[i][2] += g4[i] * bv0.z; accg[i][3] += g4[i] * bv0.w;
        accg[i][4] += g4[i] * bv1.x; accg[i][5] += g4[i] * bv1.y;
        accg[i][6] += g4[i] * bv1.z; accg[i][7] += g4[i] * bv1.w;
        accb[i][0] += c4[i] * bv0.x; accb[i][1] += c4[i] * bv0.y;
        accb[i][2] += c4[i] * bv0.z; accb[i][3] += c4[i] * bv0.w;
        accb[i][4] += c4[i] * bv1.x; accb[i][5] += c4[i] * bv1.y;
        accb[i][6] += c4[i] * bv1.z; accb[i][7] += c4[i] * bv1.w;
      }
    }
    __syncthreads();
  }

  const float* Xb = X + (size_t)b * CH * TTT;
  const float* xm = xmask + (size_t)b * TTT;
#pragma unroll
  for (int g = 0; g < 2; ++g) {
    int t = t0 + 4 * tx + 64 * g;
    float4 xmv = *(const float4*)&xm[t];
#pragma unroll
    for (int i = 0; i < 4; ++i) {
      int row = m0 + 4 * ty + i;
      float bg = bfilm[row], bb = bfilm[256 + row];
      float4 xv = *(const float4*)&Xb[(size_t)row * TTT + t];
      float4 ov;
      ov.x = (xv.x * (accg[i][4 * g + 0] + bg) + accb[i][4 * g + 0] + bb) * xmv.x;
      ov.y = (xv.y * (accg[i][4 * g + 1] + bg) + accb[i][4 * g + 1] + bb) * xmv.y;
      ov.z = (xv.z * (accg[i][4 * g + 2] + bg) + accb[i][4 * g + 2] + bb) * xmv.z;
      ov.w = (xv.w * (accg[i][4 * g + 3] + bg) + accb[i][4 * g + 3] + bb) * xmv.w;
      *(float4*)&out[((size_t)b * CH + row) * TTT + t] = ov;
    }
  }
}

// ---------------------------------------------------------------------------
extern "C" void kernel_launch(void* const* d_in, const int* in_sizes, int n_in,
                              void* d_out, int out_size, void* d_ws, size_t ws_size,
                              hipStream_t stream) {
  const float* x           = (const float*)d_in[0];
  const float* x_mask      = (const float*)d_in[1];
  const float* cond_latent = (const float*)d_in[2];
  const float* cond_mask   = (const float*)d_in[3];
  const float* w_cond      = (const float*)d_in[4];
  const float* b_cond      = (const float*)d_in[5];
  const float* wq          = (const float*)d_in[6];
  const float* bq          = (const float*)d_in[7];
  const float* wk          = (const float*)d_in[8];
  const float* bk          = (const float*)d_in[9];
  const float* wv          = (const float*)d_in[10];
  const float* bv          = (const float*)d_in[11];
  const float* wo          = (const float*)d_in[12];
  const float* bo          = (const float*)d_in[13];
  const float* w_film      = (const float*)d_in[14];
  const float* b_film      = (const float*)d_in[15];
  float* out = (float*)d_out;

  float* ws = (float*)d_ws;
  float* c_buf = ws;                    // 16*256*512
  float* q_buf = c_buf + 2097152;       // 16*256*2048 (reused as attn out)
  float* k_buf = q_buf + 8388608;
  float* v_buf = k_buf + 2097152;
  float* y_buf = v_buf + 2097152;

  dim3 blk(256);

  // c = w_cond @ cond_latent + b_cond   [16,256,512]  (K=512)
  gemm_v2<4, 1><<<dim3(8, 4, 16), blk, 0, stream>>>(
      w_cond, b_cond, nullptr, nullptr, cond_latent, c_buf, nullptr, 512, 512);
  // q = wq @ x + bq                     [16,256,2048]
  gemm_v2<8, 1><<<dim3(16, 4, 16), blk, 0, stream>>>(
      wq, bq, nullptr, nullptr, x, q_buf, nullptr, 256, 2048);
  // k,v fused                           [16,256,512]
  gemm_v2<4, 2><<<dim3(8, 4, 16), blk, 0, stream>>>(
      wk, bk, wv, bv, c_buf, k_buf, v_buf, 256, 512);
  // RoPE in place
  rope_kernel<<<16384, blk, 0, stream>>>(q_buf, 2048, 11);
  rope_kernel<<<4096, blk, 0, stream>>>(k_buf, 512, 9);
  // attention (in-place over q_buf)
  attn_v2<<<dim3(32, 4, 16), blk, 0, stream>>>(q_buf, k_buf, v_buf, cond_mask, q_buf);
  // y = wo @ attn + bo
  gemm_v2<8, 1><<<dim3(16, 4, 16), blk, 0, stream>>>(
      wo, bo, nullptr, nullptr, q_buf, y_buf, nullptr, 256, 2048);
  // film + final output
  film_v2<<<dim3(16, 4, 16), blk, 0, stream>>>(w_film, b_film, y_buf, x, x_mask, out);
}

// Round 5
// 716.870 us; speedup vs baseline: 1.1461x; 1.0155x over previous
//
#include <hip/hip_runtime.h>
#include <math.h>

#define NB 16        // batch
#define CH 256       // hidden
#define CND 512      // cond channels
#define NH 4
#define KC 64
#define TTT 2048
#define TSS 512

// ---------------------------------------------------------------------------
// Templated tiled GEMM: Yn[b] = Wn @ X[b] + bn   (n < NOUT)
// W: [M,K] row-major, X: [B,K,T], Y: [B,M,T] (row-stride 256·T per batch; fine
// for any M when B==1). Tile: 64 rows x (16*TN) cols, BK=32. Block 256.
// ---------------------------------------------------------------------------
template <int TN, int NOUT>
__global__ __launch_bounds__(256) void gemm_v2(
    const float* __restrict__ W0, const float* __restrict__ b0,
    const float* __restrict__ W1, const float* __restrict__ b1,
    const float* __restrict__ X, float* __restrict__ Y0, float* __restrict__ Y1,
    int K, int T) {
  constexpr int TT = 16 * TN;
  constexpr int TQ = TT / 4;
  constexpr int PB = (32 * TQ) / 256;
  const int t0 = blockIdx.x * TT;
  const int m0 = blockIdx.y * 64;
  const int b  = blockIdx.z;
  const int tid = threadIdx.x;
  const int tx = tid & 15, ty = tid >> 4;

  __shared__ float As[NOUT][32][68];
  __shared__ float Bs[32][TT + 4];

  const float* Xb = X + (size_t)b * K * T;
  float acc[NOUT][4][TN];
#pragma unroll
  for (int n = 0; n < NOUT; ++n)
#pragma unroll
    for (int i = 0; i < 4; ++i)
#pragma unroll
      for (int u = 0; u < TN; ++u) acc[n][i][u] = 0.f;

  const int am = tid >> 2, akq = tid & 3;

  for (int k0 = 0; k0 < K; k0 += 32) {
#pragma unroll
    for (int n = 0; n < NOUT; ++n) {
      const float* Wn = (n == 0) ? W0 : W1;
      float4 a0 = *(const float4*)&Wn[(size_t)(m0 + am) * K + k0 + 4 * akq];
      float4 a1 = *(const float4*)&Wn[(size_t)(m0 + am) * K + k0 + 16 + 4 * akq];
      As[n][4 * akq + 0][am] = a0.x; As[n][4 * akq + 1][am] = a0.y;
      As[n][4 * akq + 2][am] = a0.z; As[n][4 * akq + 3][am] = a0.w;
      As[n][16 + 4 * akq + 0][am] = a1.x; As[n][16 + 4 * akq + 1][am] = a1.y;
      As[n][16 + 4 * akq + 2][am] = a1.z; As[n][16 + 4 * akq + 3][am] = a1.w;
    }
#pragma unroll
    for (int p = 0; p < PB; ++p) {
      int idx = tid + p * 256;
      int t4 = idx & (TQ - 1), k = idx / TQ;
      *(float4*)&Bs[k][4 * t4] = *(const float4*)&Xb[(size_t)(k0 + k) * T + t0 + 4 * t4];
    }
    __syncthreads();
#pragma unroll
    for (int kk = 0; kk < 32; ++kk) {
      float4 av[NOUT];
#pragma unroll
      for (int n = 0; n < NOUT; ++n) av[n] = *(const float4*)&As[n][kk][4 * ty];
      float4 bv[TN / 4];
#pragma unroll
      for (int g = 0; g < TN / 4; ++g) bv[g] = *(const float4*)&Bs[kk][4 * tx + 64 * g];
#pragma unroll
      for (int n = 0; n < NOUT; ++n) {
        const float a4[4] = {av[n].x, av[n].y, av[n].z, av[n].w};
#pragma unroll
        for (int i = 0; i < 4; ++i)
#pragma unroll
          for (int g = 0; g < TN / 4; ++g) {
            acc[n][i][4 * g + 0] += a4[i] * bv[g].x;
            acc[n][i][4 * g + 1] += a4[i] * bv[g].y;
            acc[n][i][4 * g + 2] += a4[i] * bv[g].z;
            acc[n][i][4 * g + 3] += a4[i] * bv[g].w;
          }
      }
    }
    __syncthreads();
  }
#pragma unroll
  for (int n = 0; n < NOUT; ++n) {
    float* Yn = (n == 0) ? Y0 : Y1;
    const float* bn = (n == 0) ? b0 : b1;
#pragma unroll
    for (int i = 0; i < 4; ++i) {
      int row = m0 + 4 * ty + i;
      float bi = bn[row];
#pragma unroll
      for (int g = 0; g < TN / 4; ++g) {
        float4 ov;
        ov.x = acc[n][i][4 * g + 0] + bi; ov.y = acc[n][i][4 * g + 1] + bi;
        ov.z = acc[n][i][4 * g + 2] + bi; ov.w = acc[n][i][4 * g + 3] + bi;
        *(float4*)&Yn[((size_t)b * 256 + row) * T + t0 + 4 * tx + 64 * g] = ov;
      }
    }
  }
}

// ---------------------------------------------------------------------------
// Bias folding: bk2 = wk@b_cond + bk; bv2 = wv@b_cond + bv; bf2 = w_film@bo + b_film
// ---------------------------------------------------------------------------
__global__ __launch_bounds__(256) void bias_fold(
    const float* __restrict__ wk, const float* __restrict__ bk,
    const float* __restrict__ wv, const float* __restrict__ bv,
    const float* __restrict__ bcond,
    const float* __restrict__ wfilm, const float* __restrict__ bo,
    const float* __restrict__ bfilm,
    float* __restrict__ bk2, float* __restrict__ bv2, float* __restrict__ bf2) {
  int g = blockIdx.x * 256 + threadIdx.x;
  if (g < 256) {
    float s = bk[g];
    for (int k = 0; k < 256; ++k) s += wk[g * 256 + k] * bcond[k];
    bk2[g] = s;
  } else if (g < 512) {
    int m = g - 256;
    float s = bv[m];
    for (int k = 0; k < 256; ++k) s += wv[m * 256 + k] * bcond[k];
    bv2[m] = s;
  } else if (g < 1024) {
    int m = g - 512;
    float s = bfilm[m];
    for (int k = 0; k < 256; ++k) s += wfilm[m * 256 + k] * bo[k];
    bf2[m] = s;
  }
}

// ---------------------------------------------------------------------------
// In-place RoPE for K (q-RoPE is fused into attention staging)
// ---------------------------------------------------------------------------
__global__ __launch_bounds__(256) void rope_kernel(float* buf, int T, int tlog2) {
  int idx = blockIdx.x * 256 + threadIdx.x;
  int t = idx & (T - 1);
  int r = idx >> tlog2;
  int j = r & 31; r >>= 5;
  int h = r & 3;
  int b = r >> 2;
  if (b >= NB) return;
  float invf = expf(-(float)j * 0.28782313662425572f);
  float ang = (float)t * invf;
  float cs = cosf(ang), sn = sinf(ang);
  size_t base = ((size_t)(b * CH + h * KC + j)) * T + t;
  float q1 = buf[base];
  float q2 = buf[base + (size_t)32 * T];
  buf[base] = q1 * cs - q2 * sn;
  buf[base + (size_t)32 * T] = q2 * cs + q1 * sn;
}

// ---------------------------------------------------------------------------
// Attention v4: 128 q-rows x 128 s-cols per tile; 8x8 S-microtile, 8x4
// O-microtile. K and E SHARE one LDS buffer (K dead after S-compute; E
// written after a barrier; K restaged each tile). Fixes v3's Es[128][68]
// aliasing bug (columns up to 127 overflowed into the next row).
// Strides: Qs/K 128 (uniform-row reads), E 132 (ev reads 2-way, 16B aligned),
// V 132 (2-way). LDS total 134144 B -> 1 block/CU; saturate via ILP.
// Fragment map: rows r = 4ty+(i&3)+64*(i>>2), cols c = 4tx+(j&3)+64*(j>>2),
// O chans ch = tx+16m.
// ---------------------------------------------------------------------------
__global__ __launch_bounds__(256, 1) void attn_v4(
    const float* __restrict__ qbuf, const float* __restrict__ kbuf,
    const float* __restrict__ vbuf, const float* __restrict__ cond_mask,
    float* __restrict__ obuf) {
  const int t0 = blockIdx.x * 128;
  const int h  = blockIdx.y;
  const int b  = blockIdx.z;
  const int tid = threadIdx.x;
  const int tx = tid & 15, ty = tid >> 4;

  __shared__ float Qs[64][128];   // [ch][t]
  __shared__ float KE[16896];     // K view: [ch*128+s] (64x128); E view: [r*132+c] (128x132); O view: [ch*132+t]
  __shared__ float Vs[64][132];   // [ch][s]

  // ---- stage Q with fused RoPE (once per block) ----
  const float* qb = qbuf + ((size_t)(b * CH + h * KC)) * TTT + t0;
#pragma unroll
  for (int p = 0; p < 4; ++p) {
    int idx = tid + p * 256;
    int j = idx >> 5, t4 = idx & 31;
    float4 qa = *(const float4*)&qb[(size_t)j * TTT + 4 * t4];
    float4 qc = *(const float4*)&qb[(size_t)(j + 32) * TTT + 4 * t4];
    float invf = expf(-(float)j * 0.28782313662425572f);
    const float qav[4] = {qa.x, qa.y, qa.z, qa.w};
    const float qcv[4] = {qc.x, qc.y, qc.z, qc.w};
    float oa[4], oc[4];
#pragma unroll
    for (int e = 0; e < 4; ++e) {
      float ang = (float)(t0 + 4 * t4 + e) * invf;
      float cs = cosf(ang), sn = sinf(ang);
      oa[e] = qav[e] * cs - qcv[e] * sn;
      oc[e] = qcv[e] * cs + qav[e] * sn;
    }
    *(float4*)&Qs[j][4 * t4]      = make_float4(oa[0], oa[1], oa[2], oa[3]);
    *(float4*)&Qs[j + 32][4 * t4] = make_float4(oc[0], oc[1], oc[2], oc[3]);
  }

  float acc_o[8][4] = {};
  float dden[8] = {};

  const float* kb = kbuf + ((size_t)(b * CH + h * KC)) * TSS;
  const float* vb = vbuf + ((size_t)(b * CH + h * KC)) * TSS;
  const float* cm = cond_mask + (size_t)b * TSS;

  for (int s0 = 0; s0 < TSS; s0 += 128) {
    __syncthreads();   // (A) prior tile's PV reads of KE/Vs complete
    // ---- stage K (into KE as [ch*128+s]), V ----
#pragma unroll
    for (int p = 0; p < 8; ++p) {
      int idx = tid + p * 256;
      int ch = idx >> 5, s4 = idx & 31;
      *(float4*)&KE[ch * 128 + 4 * s4] = *(const float4*)&kb[(size_t)ch * TSS + s0 + 4 * s4];
      *(float4*)&Vs[ch][4 * s4]        = *(const float4*)&vb[(size_t)ch * TSS + s0 + 4 * s4];
    }
    __syncthreads();   // (B) staging (and first-iter Q) visible

    // ---- S = Q K^T : 8x8 frag, 4 b128 reads per j for 64 FMA ----
    float acc_s[8][8];
#pragma unroll
    for (int r = 0; r < 8; ++r)
#pragma unroll
      for (int c = 0; c < 8; ++c) acc_s[r][c] = 0.f;
#pragma unroll 4
    for (int j = 0; j < 64; ++j) {
      float4 q0 = *(const float4*)&Qs[j][4 * ty];
      float4 q1 = *(const float4*)&Qs[j][64 + 4 * ty];
      float4 k0 = *(const float4*)&KE[j * 128 + 4 * tx];
      float4 k1 = *(const float4*)&KE[j * 128 + 64 + 4 * tx];
      const float qv[8] = {q0.x, q0.y, q0.z, q0.w, q1.x, q1.y, q1.z, q1.w};
      const float kv[8] = {k0.x, k0.y, k0.z, k0.w, k1.x, k1.y, k1.z, k1.w};
#pragma unroll
      for (int r = 0; r < 8; ++r)
#pragma unroll
        for (int c = 0; c < 8; ++c) acc_s[r][c] += qv[r] * kv[c];
    }
    __syncthreads();   // (C) all K reads done; KE region becomes E

    // ---- mask + exp + E write (E view: stride 132) ----
    float mk[8];
#pragma unroll
    for (int c = 0; c < 8; ++c)
      mk[c] = (cm[s0 + 4 * tx + (c & 3) + 64 * (c >> 2)] != 0.f) ? 1.f : 0.f;
#pragma unroll
    for (int r = 0; r < 8; ++r) {
      int row = 4 * ty + (r & 3) + 64 * (r >> 2);
      float ev[8];
#pragma unroll
      for (int c = 0; c < 8; ++c) {
        ev[c] = __expf(acc_s[r][c] * 0.125f) * mk[c];
        dden[r] += ev[c];
      }
      *(float4*)&KE[row * 132 + 4 * tx]      = make_float4(ev[0], ev[1], ev[2], ev[3]);
      *(float4*)&KE[row * 132 + 64 + 4 * tx] = make_float4(ev[4], ev[5], ev[6], ev[7]);
    }
    __syncthreads();   // (D) E visible

    // ---- O += P V : 12 b128 reads per 4-s step for 128 FMA ----
#pragma unroll 2
    for (int q4 = 0; q4 < 32; ++q4) {
      float4 ev[8], vv[4];
#pragma unroll
      for (int r = 0; r < 8; ++r)
        ev[r] = *(const float4*)&KE[(4 * ty + (r & 3) + 64 * (r >> 2)) * 132 + 4 * q4];
#pragma unroll
      for (int m = 0; m < 4; ++m)
        vv[m] = *(const float4*)&Vs[tx + 16 * m][4 * q4];
#pragma unroll
      for (int r = 0; r < 8; ++r)
#pragma unroll
        for (int m = 0; m < 4; ++m)
          acc_o[r][m] += ev[r].x * vv[m].x + ev[r].y * vv[m].y +
                         ev[r].z * vv[m].z + ev[r].w * vv[m].w;
    }
  }

  // ---- row denominators: butterfly over 16 tx lanes ----
  float rd[8];
#pragma unroll
  for (int r = 0; r < 8; ++r) {
    float d = dden[r];
#pragma unroll
    for (int off = 1; off < 16; off <<= 1) d += __shfl_xor(d, off, 16);
    rd[r] = 1.f / fmaxf(d, 1e-30f);
  }

  __syncthreads();   // last PV reads of KE done; reuse KE as O [ch*132+t]
#pragma unroll
  for (int r = 0; r < 8; ++r) {
    int row = 4 * ty + (r & 3) + 64 * (r >> 2);
#pragma unroll
    for (int m = 0; m < 4; ++m)
      KE[(tx + 16 * m) * 132 + row] = acc_o[r][m] * rd[r];
  }
  __syncthreads();

  float* ob = obuf + ((size_t)(b * CH + h * KC)) * TTT + t0;
#pragma unroll
  for (int p = 0; p < 8; ++p) {
    int idx = tid + p * 256;
    int ch = idx >> 5, t4 = idx & 31;
    *(float4*)&ob[(size_t)ch * TTT + 4 * t4] = *(const float4*)&KE[ch * 132 + 4 * t4];
  }
}

// ---------------------------------------------------------------------------
// Film: gb = wf2 @ ao + bf2; out = (x*gamma + beta) * x_mask
// wf2 = w_film@wo (precomputed), bf2 = w_film@bo + b_film (precomputed).
// ---------------------------------------------------------------------------
__global__ __launch_bounds__(256) void film_v2(
    const float* __restrict__ wf, const float* __restrict__ bfilm,
    const float* __restrict__ Yb, const float* __restrict__ X,
    const float* __restrict__ xmask, float* __restrict__ out) {
  const int t0 = blockIdx.x * 128;
  const int m0 = blockIdx.y * 64;
  const int b  = blockIdx.z;
  const int tid = threadIdx.x;
  const int tx = tid & 15, ty = tid >> 4;

  __shared__ float Ag[32][68];
  __shared__ float Ab[32][68];
  __shared__ float Bs[32][132];

  const float* Y = Yb + (size_t)b * CH * TTT;
  float accg[4][8], accb[4][8];
#pragma unroll
  for (int i = 0; i < 4; ++i)
#pragma unroll
    for (int u = 0; u < 8; ++u) { accg[i][u] = 0.f; accb[i][u] = 0.f; }

  const int am = tid >> 2, akq = tid & 3;

  for (int k0 = 0; k0 < 256; k0 += 32) {
    {
      float4 a0 = *(const float4*)&wf[(size_t)(m0 + am) * 256 + k0 + 4 * akq];
      float4 a1 = *(const float4*)&wf[(size_t)(m0 + am) * 256 + k0 + 16 + 4 * akq];
      Ag[4 * akq + 0][am] = a0.x; Ag[4 * akq + 1][am] = a0.y;
      Ag[4 * akq + 2][am] = a0.z; Ag[4 * akq + 3][am] = a0.w;
      Ag[16 + 4 * akq + 0][am] = a1.x; Ag[16 + 4 * akq + 1][am] = a1.y;
      Ag[16 + 4 * akq + 2][am] = a1.z; Ag[16 + 4 * akq + 3][am] = a1.w;
      float4 c0 = *(const float4*)&wf[(size_t)(256 + m0 + am) * 256 + k0 + 4 * akq];
      float4 c1 = *(const float4*)&wf[(size_t)(256 + m0 + am) * 256 + k0 + 16 + 4 * akq];
      Ab[4 * akq + 0][am] = c0.x; Ab[4 * akq + 1][am] = c0.y;
      Ab[4 * akq + 2][am] = c0.z; Ab[4 * akq + 3][am] = c0.w;
      Ab[16 + 4 * akq + 0][am] = c1.x; Ab[16 + 4 * akq + 1][am] = c1.y;
      Ab[16 + 4 * akq + 2][am] = c1.z; Ab[16 + 4 * akq + 3][am] = c1.w;
    }
#pragma unroll
    for (int p = 0; p < 4; ++p) {
      int idx = tid + p * 256;
      int t4 = idx & 31, k = idx >> 5;
      *(float4*)&Bs[k][4 * t4] = *(const float4*)&Y[(size_t)(k0 + k) * TTT + t0 + 4 * t4];
    }
    __syncthreads();
#pragma unroll
    for (int kk = 0; kk < 32; ++kk) {
      float4 ag = *(const float4*)&Ag[kk][4 * ty];
      float4 ab = *(const float4*)&Ab[kk][4 * ty];
      float4 bv0 = *(const float4*)&Bs[kk][4 * tx];
      float4 bv1 = *(const float4*)&Bs[kk][4 * tx + 64];
      const float g4[4] = {ag.x, ag.y, ag.z, ag.w};
      const float c4[4] = {ab.x, ab.y, ab.z, ab.w};
#pragma unroll
      for (int i = 0; i < 4; ++i) {
        accg[i][0] += g4[i] * bv0.x; accg[i][1] += g4[i] * bv0.y;
        accg[i][2] += g4[i] * bv0.z; accg[i][3] += g4[i] * bv0.w;
        accg[i][4] += g4[i] * bv1.x; accg[i][5] += g4[i] * bv1.y;
        accg[i][6] += g4[i] * bv1.z; accg[i][7] += g4[i] * bv1.w;
        accb[i][0] += c4[i] * bv0.x; accb[i][1] += c4[i] * bv0.y;
        accb[i][2] += c4[i] * bv0.z; accb[i][3] += c4[i] * bv0.w;
        accb[i][4] += c4[i] * bv1.x; accb[i][5] += c4[i] * bv1.y;
        accb[i][6] += c4[i] * bv1.z; accb[i][7] += c4[i] * bv1.w;
      }
    }
    __syncthreads();
  }

  const float* Xb = X + (size_t)b * CH * TTT;
  const float* xm = xmask + (size_t)b * TTT;
#pragma unroll
  for (int g = 0; g < 2; ++g) {
    int t = t0 + 4 * tx + 64 * g;
    float4 xmv = *(const float4*)&xm[t];
#pragma unroll
    for (int i = 0; i < 4; ++i) {
      int row = m0 + 4 * ty + i;
      float bg = bfilm[row], bb = bfilm[256 + row];
      float4 xv = *(const float4*)&Xb[(size_t)row * TTT + t];
      float4 ov;
      ov.x = (xv.x * (accg[i][4 * g + 0] + bg) + accb[i][4 * g + 0] + bb) * xmv.x;
      ov.y = (xv.y * (accg[i][4 * g + 1] + bg) + accb[i][4 * g + 1] + bb) * xmv.y;
      ov.z = (xv.z * (accg[i][4 * g + 2] + bg) + accb[i][4 * g + 2] + bb) * xmv.z;
      ov.w = (xv.w * (accg[i][4 * g + 3] + bg) + accb[i][4 * g + 3] + bb) * xmv.w;
      *(float4*)&out[((size_t)b * CH + row) * TTT + t] = ov;
    }
  }
}

// ---------------------------------------------------------------------------
extern "C" void kernel_launch(void* const* d_in, const int* in_sizes, int n_in,
                              void* d_out, int out_size, void* d_ws, size_t ws_size,
                              hipStream_t stream) {
  const float* x           = (const float*)d_in[0];
  const float* x_mask      = (const float*)d_in[1];
  const float* cond_latent = (const float*)d_in[2];
  const float* cond_mask   = (const float*)d_in[3];
  const float* w_cond      = (const float*)d_in[4];
  const float* b_cond      = (const float*)d_in[5];
  const float* wq          = (const float*)d_in[6];
  const float* bq          = (const float*)d_in[7];
  const float* wk          = (const float*)d_in[8];
  const float* bk          = (const float*)d_in[9];
  const float* wv          = (const float*)d_in[10];
  const float* bv          = (const float*)d_in[11];
  const float* wo          = (const float*)d_in[12];
  const float* bo          = (const float*)d_in[13];
  const float* w_film      = (const float*)d_in[14];
  const float* b_film      = (const float*)d_in[15];
  float* out = (float*)d_out;

  float* ws = (float*)d_ws;
  float* q_buf = ws;                    // 16*256*2048 = 8,388,608 (attn out in place)
  float* k_buf = q_buf + 8388608;       // 2,097,152
  float* v_buf = k_buf + 2097152;       // 2,097,152
  float* wk2   = v_buf + 2097152;       // 256*512 = 131,072
  float* wv2   = wk2 + 131072;          // 131,072
  float* wf2   = wv2 + 131072;          // 512*256 = 131,072
  float* bk2   = wf2 + 131072;          // 256
  float* bv2   = bk2 + 256;             // 256
  float* bf2   = bv2 + 256;             // 512
  float* zbuf  = bf2 + 512;             // 512 zeros

  dim3 blk(256);

  hipMemsetAsync(zbuf, 0, 512 * sizeof(float), stream);

  // --- weight folding (tiny GEMMs, B=1) ---
  // wk2 = wk @ w_cond, wv2 = wv @ w_cond          [256,512]
  gemm_v2<4, 2><<<dim3(8, 4, 1), blk, 0, stream>>>(
      wk, zbuf, wv, zbuf, w_cond, wk2, wv2, 256, 512);
  // wf2 = w_film @ wo                              [512,256]
  gemm_v2<4, 1><<<dim3(4, 8, 1), blk, 0, stream>>>(
      w_film, zbuf, nullptr, nullptr, wo, wf2, nullptr, 256, 256);
  // bias folds
  bias_fold<<<dim3(4), blk, 0, stream>>>(wk, bk, wv, bv, b_cond,
                                         w_film, bo, b_film, bk2, bv2, bf2);

  // --- main pipeline ---
  // q = wq @ x + bq                                [16,256,2048]
  gemm_v2<8, 1><<<dim3(16, 4, 16), blk, 0, stream>>>(
      wq, bq, nullptr, nullptr, x, q_buf, nullptr, 256, 2048);
  // k = wk2 @ cond + bk2, v = wv2 @ cond + bv2     [16,256,512] (K=512)
  gemm_v2<4, 2><<<dim3(8, 4, 16), blk, 0, stream>>>(
      wk2, bk2, wv2, bv2, cond_latent, k_buf, v_buf, 512, 512);
  // RoPE on k (q-RoPE fused into attention)
  rope_kernel<<<4096, blk, 0, stream>>>(k_buf, 512, 9);
  // attention (in-place over q_buf)
  attn_v4<<<dim3(16, 4, 16), blk, 0, stream>>>(q_buf, k_buf, v_buf, cond_mask, q_buf);
  // film + final output (consumes attention output directly)
  film_v2<<<dim3(16, 4, 16), blk, 0, stream>>>(wf2, bf2, q_buf, x, x_mask, out);
}